// Round 7
// baseline (863.958 us; speedup 1.0000x reference)
//
#include <hip/hip_runtime.h>

// GRU scan: B=2048, T=2048, D=3, H=32. out[b,t] = h_new[b,t][0].
// Round-7: DUAL-STREAM + PACKED FP32.
//  r6 lesson: pure VALU-issue bound; register systolic costs MORE issue than
//  LDS gather (ds_read_b128 = 4 values/inst vs 1 for DPP/permlane).
//  Design: 2 independent batch elems per 64-lane wave (1024 blocks = 1
//  wave/SIMD). Per step: [compute A | write hA + read hkA' | compute B |
//  write hB + read hkB'] -- each LDS gather round-trip is covered by the
//  other stream's full compute, by PROGRAM ORDER (no reliance on 2nd wave).
//  Weights shared across streams (48 VGPRs). K-loop uses <2 x float>
//  elementwise-fma -> v_pk_fma_f32 (2 MACs/inst): 24 insts per elem-step.
//  Sigma-split + permlane32 combines proven in r5/r6; h valid in all lanes.

#define GRU_B 2048
#define GRU_T 2048
#define GRU_D 3
#define GRU_H 32
#define CHUNK 16
#define NCHUNK (GRU_T / CHUNK)

typedef int   v2i __attribute__((ext_vector_type(2)));
typedef float v2f __attribute__((ext_vector_type(2)));
typedef float v4f __attribute__((ext_vector_type(4)));

__device__ __forceinline__ float fast_sigmoid(float x) {
    float e = __expf(-x);                       // v_mul(log2e)+v_exp
    return __builtin_amdgcn_rcpf(1.0f + e);     // e=inf -> 0 (correct limit)
}
__device__ __forceinline__ float fast_tanh(float x) {
    float e = __expf(2.0f * x);                 // overflow -> inf -> tanh=1
    return 1.0f - 2.0f * __builtin_amdgcn_rcpf(e + 1.0f);
}

#if __has_builtin(__builtin_amdgcn_permlane32_swap)
// lo_b = [v_lo32 bcast], hi_b = [v_hi32 bcast] (HW-verified in r5/r6)
__device__ __forceinline__ void bcast32(float v, float& lo_b, float& hi_b) {
    v2i r = __builtin_amdgcn_permlane32_swap(__float_as_int(v), __float_as_int(v),
                                             false, false);
    lo_b = __int_as_float(r.x);
    hi_b = __int_as_float(r.y);
}
#else
__device__ __forceinline__ void bcast32(float v, float& lo_b, float& hi_b) {
    int paddr = (int)((threadIdx.x ^ 32u) << 2);
    float o = __int_as_float(__builtin_amdgcn_ds_bpermute(paddr, __float_as_int(v)));
    bool lo = threadIdx.x < 32;
    lo_b = lo ? v : o;
    hi_b = lo ? o : v;
}
#endif

__device__ __forceinline__ float rdlanef(float v, int idx) {
    return __int_as_float(__builtin_amdgcn_readlane(__float_as_int(v), idx));
}

// One GRU step for one stream. hk4 = this elem's gathered h window (4x b128),
// weights shared across streams. Returns h_new, valid in ALL lanes.
__device__ __forceinline__ float gru_step(
    const v4f hk4[4], const v2f* wa, const v2f* wb, const v2f* wc,
    const float* wia, const float* wic, float bA, float bC,
    float x0, float x1, float x2, bool lo32, float h)
{
    v2f A2 = {0.0f, 0.0f}, B2 = {0.0f, 0.0f}, C2 = {0.0f, 0.0f};
#pragma unroll
    for (int q = 0; q < 4; ++q) {
        const v2f hlo = hk4[q].xy;   // pairs stay even-aligned from ds_read_b128
        const v2f hhi = hk4[q].zw;
        A2 = __builtin_elementwise_fma(wa[2*q],   hlo, A2);
        B2 = __builtin_elementwise_fma(wb[2*q],   hlo, B2);
        C2 = __builtin_elementwise_fma(wc[2*q],   hlo, C2);
        A2 = __builtin_elementwise_fma(wa[2*q+1], hhi, A2);
        B2 = __builtin_elementwise_fma(wb[2*q+1], hhi, B2);
        C2 = __builtin_elementwise_fma(wc[2*q+1], hhi, C2);
    }
    const float A  = A2.x + A2.y;
    const float Bp = B2.x + B2.y;
    const float Cp = C2.x + C2.y;

    const float aM = fmaf(wia[2], x2, fmaf(wia[1], x1, fmaf(wia[0], x0, bA)));
    const float aN = fmaf(wic[2], x2, fmaf(wic[1], x1, fmaf(wic[0], x0, bC)));

    float cLo, cHi; bcast32(Cp, cLo, cHi);
    const float gN = cLo + cHi;                    // full n-dot, all lanes
    float bLo, bHi; bcast32(Bp, bLo, bHi);
    const float gM = aM + A + (lo32 ? bHi : bLo);  // my sigmoid gate, full

    const float sg = fast_sigmoid(gM);             // half0: r, half1: z
    float rAll, zAll; bcast32(sg, rAll, zAll);     // r and z in all lanes

    const float n = fast_tanh(fmaf(rAll, gN, aN));
    return fmaf(zAll, h - n, n);                   // (1-z)*n + z*h, all lanes
}

__global__ __launch_bounds__(64, 1) void gru_scan_kernel(
    const float* __restrict__ inp,     // [B, T, D]
    const float* __restrict__ w_ih,    // [3H, D]
    const float* __restrict__ w_hh,    // [3H, H]
    const float* __restrict__ bias,    // [3H]
    const float* __restrict__ bias_n,  // [H]
    float* __restrict__ out)           // [B, T]
{
    // per-elem LDS: [0..31] the h copy, [64..95] dump rows for the idle half
    __shared__ __align__(16) float h2A[96];
    __shared__ __align__(16) float h2B[96];

    const int lane = threadIdx.x;        // 0..63
    const int unit = lane & 31;
    const int half = lane >> 5;          // K-half: 0 -> k 0..15, 1 -> k 16..31
    const bool lo32 = (lane < 32);
    const int bA_ = blockIdx.x * 2;
    const int bB_ = bA_ + 1;

    // Gate rows (sigma-split, proven r5/r6)
    const int rowA = unit + 32 * half;           // my sigmoid gate
    const int rowB = unit + 32 * (1 - half);     // other sigmoid gate (to send)
    const int rowC = 2 * GRU_H + unit;           // n gate
    const int kofs = 16 * half;

    // Shared weights, packed as v2f pairs (24 pairs = 48 VGPRs)
    v2f wa[8], wb[8], wc[8];
    {
        const v4f* pa = (const v4f*)(w_hh + (size_t)rowA * GRU_H + kofs);
        const v4f* pb = (const v4f*)(w_hh + (size_t)rowB * GRU_H + kofs);
        const v4f* pc = (const v4f*)(w_hh + (size_t)rowC * GRU_H + kofs);
#pragma unroll
        for (int q = 0; q < 4; ++q) {
            v4f A = pa[q], Bv = pb[q], Cv = pc[q];
            wa[2*q] = A.xy;  wa[2*q+1] = A.zw;
            wb[2*q] = Bv.xy; wb[2*q+1] = Bv.zw;
            wc[2*q] = Cv.xy; wc[2*q+1] = Cv.zw;
        }
    }
    float wia[GRU_D], wic[GRU_D];
#pragma unroll
    for (int d = 0; d < GRU_D; ++d) {
        wia[d] = w_ih[(size_t)rowA * GRU_D + d];
        wic[d] = w_ih[(size_t)rowC * GRU_D + d];
    }
    const float bAg = bias[rowA];
    const float bCg = bias[rowC] + bias_n[unit];

    const float* xbA = inp + (size_t)bA_ * GRU_T * GRU_D;
    const float* xbB = inp + (size_t)bB_ * GRU_T * GRU_D;
    float* obA = out + (size_t)bA_ * GRU_T;
    float* obB = out + (size_t)bB_ * GRU_T;

    // h write targets: real copy written by half0 for A, half1 for B; the
    // other half hits a dump row (unpredicated, 2-way alias = free).
    const int wbaseA = unit + 64 * half;
    const int wbaseB = unit + 64 * (1 - half);

    if (lane < 32) { h2A[lane] = 0.0f; h2B[lane] = 0.0f; }
    // same-wave DS ops are pipe-ordered: reads below see these writes.

    const v4f* hvA = (const v4f*)(h2A + kofs);
    const v4f* hvB = (const v4f*)(h2B + kofs);

    v4f hk4A[4], hk4B[4];
#pragma unroll
    for (int q = 0; q < 4; ++q) { hk4A[q] = hvA[q]; hk4B[q] = hvB[q]; }

    float hA = 0.0f, hB = 0.0f;
    float outA = 0.0f, outB = 0.0f;

    // x chunk staging: lane i holds x_chunk[i] (48 floats), prefetch 1 ahead
    float vxA = (lane < CHUNK * GRU_D) ? xbA[lane] : 0.0f;
    float vxB = (lane < CHUNK * GRU_D) ? xbB[lane] : 0.0f;

    for (int c = 0; c < NCHUNK; ++c) {
        const int cn = (c + 1 < NCHUNK) ? c + 1 : c;
        float vxA_n = (lane < CHUNK * GRU_D) ? xbA[cn * CHUNK * GRU_D + lane] : 0.0f;
        float vxB_n = (lane < CHUNK * GRU_D) ? xbB[cn * CHUNK * GRU_D + lane] : 0.0f;

#pragma unroll 4
        for (int s = 0; s < CHUNK; ++s) {
            // ---- stream A: compute (gather was issued one elem-compute ago) ----
            {
                const float x0 = rdlanef(vxA, 3 * s + 0);
                const float x1 = rdlanef(vxA, 3 * s + 1);
                const float x2 = rdlanef(vxA, 3 * s + 2);
                hA = gru_step(hk4A, wa, wb, wc, wia, wic, bAg, bCg,
                              x0, x1, x2, lo32, hA);
                h2A[wbaseA] = hA;                     // write h (real + dump)
#pragma unroll
                for (int q = 0; q < 4; ++q) hk4A[q] = hvA[q];  // next-step gather
                if (lane == s) outA = rdlanef(hA, 0); // capture out[t]=h[0]
            }
            // ---- stream B: compute (covers A's gather latency) ----
            {
                const float x0 = rdlanef(vxB, 3 * s + 0);
                const float x1 = rdlanef(vxB, 3 * s + 1);
                const float x2 = rdlanef(vxB, 3 * s + 2);
                hB = gru_step(hk4B, wa, wb, wc, wia, wic, bAg, bCg,
                              x0, x1, x2, lo32, hB);
                h2B[wbaseB] = hB;
#pragma unroll
                for (int q = 0; q < 4; ++q) hk4B[q] = hvB[q];
                if (lane == s) outB = rdlanef(hB, 0);
            }
        }

        if (lane < CHUNK) {
            obA[c * CHUNK + lane] = outA;   // coalesced 64B stores
            obB[c * CHUNK + lane] = outB;
        }
        vxA = vxA_n; vxB = vxB_n;
    }
}

extern "C" void kernel_launch(void* const* d_in, const int* in_sizes, int n_in,
                              void* d_out, int out_size, void* d_ws, size_t ws_size,
                              hipStream_t stream) {
    const float* inp    = (const float*)d_in[0];
    const float* w_ih   = (const float*)d_in[1];
    const float* w_hh   = (const float*)d_in[2];
    const float* bias   = (const float*)d_in[3];
    const float* bias_n = (const float*)d_in[4];
    float* out = (float*)d_out;

    dim3 grid(GRU_B / 2);
    dim3 block(64);
    gru_scan_kernel<<<grid, block, 0, stream>>>(inp, w_ih, w_hh, bias, bias_n, out);
}